// Round 13
// baseline (471.262 us; speedup 1.0000x reference)
//
#include <hip/hip_runtime.h>

// B=4, T=8, H=W=16, C=F=256, gates 4F=1024. K = 9*256 = 2304.
// Round 13: r12 structure with the LDS WAR hazard fixed — 6-buffer A ring
// (compute 2 + pending 2 + staging 2), static buffer indices from the
// 3-body rotation. 18 barriers, uniform vmcnt(6), xg prefetch, merged wprep.
#define HW      256
#define COUT    1024
#define TSTEPS  8
#define BN_EPS  1e-3f
#define KTOT    2304

typedef unsigned short u16;
typedef unsigned int   u32;
typedef __attribute__((ext_vector_type(8))) _Float16 v8h;  // 8 x fp16
typedef __attribute__((ext_vector_type(4))) float v4f;

__device__ __forceinline__ u16 f2h(float x) {
    _Float16 h = (_Float16)x; return *(u16*)&h;
}
__device__ __forceinline__ float h2f(u16 u) {
    _Float16 h = *(_Float16*)&u; return (float)h;
}
__device__ __forceinline__ float hsig(float x) {
    return fminf(fmaxf(0.2f * x + 0.5f, 0.f), 1.f);
}

typedef __attribute__((address_space(1))) const unsigned int gas_u32;
typedef __attribute__((address_space(3))) unsigned int las_u32;
__device__ __forceinline__ void gl16(const void* g, void* l) {
    __builtin_amdgcn_global_load_lds((gas_u32*)g, (las_u32*)l, 16, 0, 0);
}

// ---------------------------------------------------------------------------
// Big input conv: M=8192, N'=1024, BM=BN=128, BK=64, 4 waves (2x2),
// r6 single-barrier depth-2 pipeline, slot-swizzled LDS, 2 blk/CU.
// ---------------------------------------------------------------------------
__global__ __launch_bounds__(256, 2) void conv_big_k(
    const u16* __restrict__ apad,     // (32,18,18,256) fp16 zero-padded
    const u16* __restrict__ wT,       // (1024 n', 2304) fp16
    const float* __restrict__ bias,   // (1024) original n order
    u16* __restrict__ out)            // (8192, 1024) fp16, n' order
{
    constexpr int KQ = 36;
    __shared__ u16 lds[2 * 16384];

    const int bid = blockIdx.x;
    const int xcd = bid & 7, idx = bid >> 3;
    const int by = (xcd >> 1) * 2 + (idx & 1);
    const int bx = (xcd & 1) * 32 + (idx >> 1);
    const int m0 = bx * 128, n0 = by * 128;
    const int tid = threadIdx.x, lane = tid & 63, w = tid >> 6;
    const int wr = w >> 1, wc = w & 1;
    const int lr = lane >> 3;
    const int g  = (lane & 7) ^ lr;
    const int fr = lane & 15, kc = lane >> 4;

    const char* a_src[4];
    #pragma unroll
    for (int i = 0; i < 4; ++i) {
        int m = m0 + w * 32 + i * 8 + lr;
        int img = m >> 8, pix = m & 255, yy = pix >> 4, xx = pix & 15;
        a_src[i] = (const char*)apad + ((((long)img * 18 + yy) * 18 + xx) * 256 + g * 8) * 2;
    }
    const char* b_src[4];
    #pragma unroll
    for (int i = 0; i < 4; ++i) {
        int n = n0 + w * 32 + i * 8 + lr;
        b_src[i] = (const char*)wT + ((long)n * KTOT + g * 8) * 2;
    }

    int aro[4][2], bro[4][2];
    #pragma unroll
    for (int mi = 0; mi < 4; ++mi) {
        int rl = wr * 64 + mi * 16 + fr;
        #pragma unroll
        for (int ks = 0; ks < 2; ++ks)
            aro[mi][ks] = rl * 128 + ((((ks << 2) | kc) ^ (fr & 7)) << 4);
    }
    #pragma unroll
    for (int ni = 0; ni < 4; ++ni) {
        int nr = wc * 64 + ni * 16 + fr;
        #pragma unroll
        for (int ks = 0; ks < 2; ++ks)
            bro[ni][ks] = 16384 + nr * 128 + ((((ks << 2) | kc) ^ (fr & 7)) << 4);
    }

    v4f acc[4][4];
    #pragma unroll
    for (int mi = 0; mi < 4; ++mi)
        #pragma unroll
        for (int ni = 0; ni < 4; ++ni) acc[mi][ni] = (v4f)0.f;

#define STAGE_B(J) { int j_ = (J); int dxy = j_ >> 2, c64 = j_ & 3;           \
    int dy = (dxy * 11) >> 5; int dx = dxy - dy * 3;                          \
    int aoff = ((dy * 18 + dx) * 256 + c64 * 64) * 2; int boff = j_ * 128;    \
    char* base = (char*)lds + (j_ & 1) * 32768;                               \
    _Pragma("unroll") for (int i = 0; i < 4; ++i)                             \
        gl16(a_src[i] + aoff, base + (w * 32 + i * 8) * 128);                 \
    _Pragma("unroll") for (int i = 0; i < 4; ++i)                             \
        gl16(b_src[i] + boff, base + 16384 + (w * 32 + i * 8) * 128); }

#define COMPUTE_B(J) { const char* base = (const char*)lds + ((J) & 1) * 32768; \
    v8h af[4][2], bf[4][2];                                                   \
    _Pragma("unroll") for (int mi = 0; mi < 4; ++mi)                          \
        _Pragma("unroll") for (int ks = 0; ks < 2; ++ks)                      \
            af[mi][ks] = *(const v8h*)(base + aro[mi][ks]);                   \
    _Pragma("unroll") for (int ni = 0; ni < 4; ++ni)                          \
        _Pragma("unroll") for (int ks = 0; ks < 2; ++ks)                      \
            bf[ni][ks] = *(const v8h*)(base + bro[ni][ks]);                   \
    __builtin_amdgcn_s_setprio(1);                                            \
    _Pragma("unroll") for (int ks = 0; ks < 2; ++ks)                          \
    _Pragma("unroll") for (int mi = 0; mi < 4; ++mi)                          \
    _Pragma("unroll") for (int ni = 0; ni < 4; ++ni)                          \
        acc[mi][ni] = __builtin_amdgcn_mfma_f32_16x16x32_f16(af[mi][ks], bf[ni][ks], acc[mi][ni], 0, 0, 0); \
    __builtin_amdgcn_s_setprio(0); }

    STAGE_B(0);
    for (int kq = 0; kq < KQ - 1; ++kq) {
        asm volatile("s_waitcnt vmcnt(0)" ::: "memory");
        __builtin_amdgcn_s_barrier();
        __builtin_amdgcn_sched_barrier(0);
        STAGE_B(kq + 1);
        COMPUTE_B(kq);
    }
    asm volatile("s_waitcnt vmcnt(0)" ::: "memory");
    __builtin_amdgcn_s_barrier();
    __builtin_amdgcn_sched_barrier(0);
    COMPUTE_B(KQ - 1);
#undef STAGE_B
#undef COMPUTE_B

    #pragma unroll
    for (int mi = 0; mi < 4; ++mi) {
        #pragma unroll
        for (int ni = 0; ni < 4; ++ni) {
            int mrow = m0 + wr * 64 + mi * 16 + ((lane >> 4) << 2);
            int ncol = n0 + wc * 64 + ni * 16 + fr;
            float b0 = bias[(ncol & 3) * 256 + (ncol >> 2)];
            #pragma unroll
            for (int r = 0; r < 4; ++r)
                out[(long)(mrow + r) * COUT + ncol] = f2h(acc[mi][ni][r] + b0);
        }
    }
}

// ---------------------------------------------------------------------------
// Recurrent conv + fused LSTM cell, v9: 64x64 tile, 256 blocks (1/CU),
// 8 waves (512 thr, 2m x 4n), wave 32m x 16n. BK=128 bodies, 18 barriers,
// 6-buffer LDS A-ring (compute2 + pending2 + stage2), uniform vmcnt(6),
// 3-set B register rotation, xg epilogue prefetch issued first.
// ---------------------------------------------------------------------------
__global__ __launch_bounds__(512) void rec_fused_k(
    const u16* __restrict__ ph_in,    // (4,18,18,256) fp16  h_{t-1}
    const u16* __restrict__ wTf,      // frag-packed Wh: (64 nf, 72 k32, 512)
    const u16* __restrict__ xg,       // (8192, 1024) fp16, n' order (incl bias)
    float* __restrict__ cbuf,         // (4,256,256)
    float* __restrict__ hs,           // (4,8,256,256)
    u16* __restrict__ ph_out,         // (4,18,18,256) fp16  h_t
    int t)
{
    __shared__ u16 lds[6 * 4096];     // 6 bufs x 8KB (A only), 48KB

    const int bid = blockIdx.x;       // 256: by-pairs per XCD (bijective)
    const int by = (bid & 7) * 2 + ((bid >> 3) & 1);   // 0..15
    const int bx = bid >> 4;                           // 0..15
    const int m0 = bx * 64, n0 = by * 64;
    const int tid = threadIdx.x, lane = tid & 63, w = tid >> 6;
    const int wr = w >> 2, wc = w & 3;
    const int fr = lane & 15, kc = lane >> 4;

    // epilogue coordinates (fixed) — xg prefetch issued FIRST (2 VMEM ops;
    // they are drained by the first body's vmcnt(6))
    const int f4  = n0 + wc * 16 + (lane & 12);
    const int fch = f4 >> 2;
    int erow[2]; long xrow[2];
    uint2 xb_pre[2];
    #pragma unroll
    for (int mi = 0; mi < 2; ++mi) {
        erow[mi] = m0 + wr * 32 + mi * 16 + ((lane >> 4) << 2) + (lane & 3);
        int img = erow[mi] >> 8, pix = erow[mi] & 255;
        xrow[mi] = ((long)(img * TSTEPS + t) * HW + pix);
        xb_pre[mi] = *(const uint2*)&xg[xrow[mi] * COUT + f4];
    }

    // A staging: thread stages row rt = tid>>3 (0..63), slot lane&7
    const char* a_src;
    {
        int rt = tid >> 3;
        int gg = (tid & 7) ^ (rt & 7);     // inverse swizzle on SOURCE granule
        int m = m0 + rt;
        int img = m >> 8, pix = m & 255, yy = pix >> 4, xx = pix & 15;
        a_src = (const char*)ph_in + ((((long)img * 18 + yy) * 18 + xx) * 256 + gg * 8) * 2;
    }
    // B fragment base: wave-col owns nf = by*4 + wc
    const char* b_base = (const char*)wTf + ((long)(by * 4 + wc) * 72) * 1024 + lane * 16;

    // A frag read offsets (swizzled slot), rows wr*32 + mi*16 + fr
    int aro[2][2];
    #pragma unroll
    for (int mi = 0; mi < 2; ++mi)
        #pragma unroll
        for (int ks = 0; ks < 2; ++ks)
            aro[mi][ks] = (wr * 32 + mi * 16 + fr) * 128 + ((((ks << 2) | kc) ^ (fr & 7)) << 4);

    v4f acc0 = (v4f)0.f, acc1 = (v4f)0.f;

#define STAGE_A(J, BUF) { int j_ = (J); int dxy = j_ >> 2, c64 = j_ & 3;      \
    int dy = (dxy * 11) >> 5; int dx = dxy - dy * 3;                          \
    int aoff = ((dy * 18 + dx) * 256 + c64 * 64) * 2;                         \
    gl16(a_src + aoff, (char*)lds + (BUF) * 8192 + w * 1024); }

#define LDB(J, R0, R1) { R0 = *(const v8h*)(b_base + (2 * (J)) * 1024);       \
                         R1 = *(const v8h*)(b_base + (2 * (J) + 1) * 1024); }

// compute one kq from LDS buffer BUF with B regs C0,C1
#define CKQ(BUF, C0, C1) {                                                    \
    const char* base_ = (const char*)lds + (BUF) * 8192;                      \
    v8h af00_ = *(const v8h*)(base_ + aro[0][0]);                             \
    v8h af10_ = *(const v8h*)(base_ + aro[1][0]);                             \
    v8h af01_ = *(const v8h*)(base_ + aro[0][1]);                             \
    v8h af11_ = *(const v8h*)(base_ + aro[1][1]);                             \
    __builtin_amdgcn_s_setprio(1);                                            \
    acc0 = __builtin_amdgcn_mfma_f32_16x16x32_f16(af00_, C0, acc0, 0, 0, 0);  \
    acc1 = __builtin_amdgcn_mfma_f32_16x16x32_f16(af10_, C0, acc1, 0, 0, 0);  \
    acc0 = __builtin_amdgcn_mfma_f32_16x16x32_f16(af01_, C1, acc0, 0, 0, 0);  \
    acc1 = __builtin_amdgcn_mfma_f32_16x16x32_f16(af11_, C1, acc1, 0, 0, 0);  \
    __builtin_amdgcn_s_setprio(0); }

// body: compute kq=q0,q0+1 from bufs BC,BC+1; stage kq=q0+4,q0+5 into BS,BS+1
#define BODY2(J2, BC, BS, Ca0, Ca1, Cb0, Cb1, La0, La1, Lb0, Lb1) {           \
    int q0_ = 2 * (J2);                                                       \
    asm volatile("s_waitcnt vmcnt(6)" ::: "memory");                          \
    __builtin_amdgcn_s_barrier();                                             \
    __builtin_amdgcn_sched_barrier(0);                                        \
    LDB(q0_ + 4, La0, La1); LDB(q0_ + 5, Lb0, Lb1);                           \
    STAGE_A(q0_ + 4, BS); STAGE_A(q0_ + 5, (BS) + 1);                         \
    CKQ(BC,       Ca0, Ca1);                                                  \
    CKQ((BC) + 1, Cb0, Cb1); }

    v8h S00, S01, S02, S03, S10, S11, S12, S13, S20, S21, S22, S23;
    // prologue: body0 data then body1 data (bufs 0..3)
    LDB(0, S00, S01); LDB(1, S02, S03); STAGE_A(0, 0); STAGE_A(1, 1);
    LDB(2, S10, S11); LDB(3, S12, S13); STAGE_A(2, 2); STAGE_A(3, 3);

    for (int j = 0; j < 5; ++j) {        // bodies 0..14 (kq advances 6 per j)
        BODY2(3 * j,     0, 4, S00, S01, S02, S03, S20, S21, S22, S23);
        BODY2(3 * j + 1, 2, 0, S10, S11, S12, S13, S00, S01, S02, S03);
        BODY2(3 * j + 2, 4, 2, S20, S21, S22, S23, S10, S11, S12, S13);
    }
    // body 15 (kq 30,31 from bufs 0,1; stages kq 34,35 into bufs 4,5)
    BODY2(15, 0, 4, S00, S01, S02, S03, S20, S21, S22, S23);
    // body 16 (kq 32,33 from bufs 2,3; no issue)
    asm volatile("s_waitcnt vmcnt(6)" ::: "memory");
    __builtin_amdgcn_s_barrier();
    __builtin_amdgcn_sched_barrier(0);
    CKQ(2, S10, S11);
    CKQ(3, S12, S13);
    // body 17 (kq 34,35 from bufs 4,5; no issue)
    asm volatile("s_waitcnt vmcnt(0)" ::: "memory");
    __builtin_amdgcn_s_barrier();
    __builtin_amdgcn_sched_barrier(0);
    CKQ(4, S20, S21);
    CKQ(5, S22, S23);
#undef STAGE_A
#undef LDB
#undef CKQ
#undef BODY2

    // epilogue: quad-transpose (gate-lane <-> row-reg), + xg(prefetched), cell update.
    v4f accA[2] = {acc0, acc1};
    const bool gl0 = lane & 1, gl1 = lane & 2;
    #pragma unroll
    for (int mi = 0; mi < 2; ++mi) {
        float V0 = accA[mi][0], V1 = accA[mi][1];
        float V2 = accA[mi][2], V3 = accA[mi][3];
        float x0 = __shfl_xor(V0, 1), x1 = __shfl_xor(V1, 1);
        float x2 = __shfl_xor(V2, 1), x3 = __shfl_xor(V3, 1);
        float a0 = gl0 ? x1 : V0;
        float a1 = gl0 ? V1 : x0;
        float a2 = gl0 ? x3 : V2;
        float a3 = gl0 ? V3 : x2;
        float s0 = __shfl_xor(a0, 2), s1 = __shfl_xor(a1, 2);
        float s2 = __shfl_xor(a2, 2), s3 = __shfl_xor(a3, 2);
        float Ti = gl1 ? s2 : a0;
        float Tf = gl1 ? s3 : a1;
        float Tc = gl1 ? a2 : s0;
        float To = gl1 ? a3 : s1;

        float pi = Ti + h2f((u16)(xb_pre[mi].x & 0xffff));
        float pf = Tf + h2f((u16)(xb_pre[mi].x >> 16));
        float pc = Tc + h2f((u16)(xb_pre[mi].y & 0xffff));
        float po = To + h2f((u16)(xb_pre[mi].y >> 16));
        long cidx = (long)erow[mi] * 256 + fch;
        float c = hsig(pf) * cbuf[cidx] + hsig(pi) * tanhf(pc);
        float h = hsig(po) * tanhf(c);
        cbuf[cidx] = c;
        hs[xrow[mi] * 256 + fch] = h;
        int pix = erow[mi] & 255, img = erow[mi] >> 8;
        ph_out[(((long)img * 18 + (pix >> 4) + 1) * 18 + (pix & 15) + 1) * 256 + fch] = f2h(h);
    }
}

// ---------------------------------------------------------------------------
// t=0 cell: h0=0 -> gates = xg only (no conv). Writes cbuf/hs/ph_out.
// ---------------------------------------------------------------------------
__global__ __launch_bounds__(256) void gates0_k(
    const u16* __restrict__ xg, float* __restrict__ cbuf,
    float* __restrict__ hs, u16* __restrict__ ph_out)
{
    int idx = blockIdx.x * 256 + threadIdx.x;     // 0..262143
    int fch = idx & 255, row = idx >> 8;
    int img = row >> 8, pix = row & 255;
    long xrow = (long)(img * TSTEPS) * HW + pix;
    uint2 xb = *(const uint2*)&xg[xrow * COUT + fch * 4];
    float pi = h2f((u16)(xb.x & 0xffff));
    float pc = h2f((u16)(xb.y & 0xffff));
    float po = h2f((u16)(xb.y >> 16));
    float c = hsig(pi) * tanhf(pc);
    float h = hsig(po) * tanhf(c);
    cbuf[(long)row * 256 + fch] = c;
    hs[xrow * 256 + fch] = h;
    int yy = pix >> 4, xx = pix & 15;
    ph_out[(((long)img * 18 + yy + 1) * 18 + xx + 1) * 256 + fch] = f2h(h);
}

// ---------------------------------------------------------------------------
// merged weight prep: by<4 -> row-major wT (conv_big); by>=4 -> frag wTf (rec)
// ---------------------------------------------------------------------------
__global__ __launch_bounds__(256) void wprep_all_k(
    const float* __restrict__ wx, const float* __restrict__ wh,
    u16* __restrict__ wT, u16* __restrict__ wTf)
{
    int kq = blockIdx.x;                          // 0..71
    int by = blockIdx.y;                          // 0..19
    if (by < 4) {
        int k0 = kq * 32;
        int np = by * 256 + threadIdx.x;          // n' row
        int n  = (np & 3) * 256 + (np >> 2);
        u32 pk[16];
        #pragma unroll
        for (int kk = 0; kk < 32; kk += 2) {
            float a = wx[(long)(k0 + kk) * COUT + n];
            float b = wx[(long)(k0 + kk + 1) * COUT + n];
            pk[kk >> 1] = (u32)f2h(a) | ((u32)f2h(b) << 16);
        }
        uint4* dst = (uint4*)&wT[(long)np * KTOT + k0];
        dst[0] = make_uint4(pk[0], pk[1], pk[2], pk[3]);
        dst[1] = make_uint4(pk[4], pk[5], pk[6], pk[7]);
        dst[2] = make_uint4(pk[8], pk[9], pk[10], pk[11]);
        dst[3] = make_uint4(pk[12], pk[13], pk[14], pk[15]);
    } else {
        int nf = (by - 4) * 4 + (threadIdx.x >> 6);
        int l  = threadIdx.x & 63;
        int np = nf * 16 + (l & 15);
        int n  = (np & 3) * 256 + (np >> 2);
        int k0 = kq * 32 + (l >> 4) * 8;
        u32 pk[4];
        #pragma unroll
        for (int e = 0; e < 8; e += 2) {
            float a = wh[(long)(k0 + e) * COUT + n];
            float b = wh[(long)(k0 + e + 1) * COUT + n];
            pk[e >> 1] = (u32)f2h(a) | ((u32)f2h(b) << 16);
        }
        *(uint4*)&wTf[((long)(nf * 72) + kq) * 512 + l * 8] =
            make_uint4(pk[0], pk[1], pk[2], pk[3]);
    }
}

// ---------------------------------------------------------------------------
// convert input x (32,16,16,256) fp32 -> pad_x interior fp16
// ---------------------------------------------------------------------------
__global__ __launch_bounds__(256) void convert_x_k(const float* __restrict__ x,
                                                   u16* __restrict__ padx)
{
    int q = blockIdx.x * 256 + threadIdx.x;
    int e0 = q * 4;
    int f = e0 & 255, pix = (e0 >> 8) & 255, img = e0 >> 16;
    float4 v = ((const float4*)x)[q];
    int yy = pix >> 4, xx = pix & 15;
    long o = (((long)img * 18 + yy + 1) * 18 + xx + 1) * 256 + f;
    u32 lo = (u32)f2h(v.x) | ((u32)f2h(v.y) << 16);
    u32 hi = (u32)f2h(v.z) | ((u32)f2h(v.w) << 16);
    *(uint2*)&padx[o] = make_uint2(lo, hi);
}

// ---------------------------------------------------------------------------
// BatchNorm: deterministic two-stage stats + apply
// ---------------------------------------------------------------------------
__global__ __launch_bounds__(256) void bn_stats1_k(
    const float* __restrict__ x, float* __restrict__ partial)
{
    const int tid = threadIdx.x;
    const int blk = blockIdx.x;                // 64 blocks
    float s = 0.f, s2 = 0.f;
    const long base = (long)blk * 128 * 256;
    #pragma unroll 8
    for (int gi = 0; gi < 128; ++gi) {
        float v = x[base + gi * 256 + tid];
        s += v; s2 += v * v;
    }
    partial[blk * 512 + tid]       = s;
    partial[blk * 512 + 256 + tid] = s2;
}

__global__ __launch_bounds__(256) void bn_stats2_k(
    const float* __restrict__ partial, const float* __restrict__ gamma,
    const float* __restrict__ beta, float* __restrict__ stats)
{
    const int f = threadIdx.x;
    float s = 0.f, s2 = 0.f;
    #pragma unroll 8
    for (int b = 0; b < 64; ++b) {
        s  += partial[b * 512 + f];
        s2 += partial[b * 512 + 256 + f];
    }
    const float inv_n = 1.f / 8192.f;
    float mu  = s * inv_n;
    float var = s2 * inv_n - mu * mu;
    float sc  = gamma[f] * rsqrtf(var + BN_EPS);
    stats[f]       = sc;
    stats[256 + f] = beta[f] - mu * sc;
}

__global__ __launch_bounds__(256) void bn_apply_k(
    const float* __restrict__ x, const float* __restrict__ stats,
    u16* __restrict__ padx, float* __restrict__ out)
{
    const int q = blockIdx.x * 256 + threadIdx.x;
    const int e0 = q * 4;
    const int f = e0 & 255, pix = (e0 >> 8) & 255, img = e0 >> 16;
    float4 v  = ((const float4*)x)[q];
    float4 sc = *(const float4*)(stats + f);
    float4 sh = *(const float4*)(stats + 256 + f);
    v.x = v.x * sc.x + sh.x;
    v.y = v.y * sc.y + sh.y;
    v.z = v.z * sc.z + sh.z;
    v.w = v.w * sc.w + sh.w;
    if (out) ((float4*)out)[q] = v;
    if (padx) {
        int yy = pix >> 4, xx = pix & 15;
        long o = (((long)img * 18 + yy + 1) * 18 + xx + 1) * 256 + f;
        u32 lo = (u32)f2h(v.x) | ((u32)f2h(v.y) << 16);
        u32 hi = (u32)f2h(v.z) | ((u32)f2h(v.w) << 16);
        *(uint2*)&padx[o] = make_uint2(lo, hi);
    }
}

// ---------------------------------------------------------------------------
extern "C" void kernel_launch(void* const* d_in, const int* in_sizes, int n_in,
                              void* d_out, int out_size, void* d_ws, size_t ws_size,
                              hipStream_t stream)
{
    const float* x0    = (const float*)d_in[0];
    const float* Wx[3] = {(const float*)d_in[1], (const float*)d_in[6],  (const float*)d_in[11]};
    const float* Wh[3] = {(const float*)d_in[2], (const float*)d_in[7],  (const float*)d_in[12]};
    const float* bb[3] = {(const float*)d_in[3], (const float*)d_in[8],  (const float*)d_in[13]};
    const float* gg[3] = {(const float*)d_in[4], (const float*)d_in[9],  (const float*)d_in[14]};
    const float* be[3] = {(const float*)d_in[5], (const float*)d_in[10], (const float*)d_in[15]};

    float* ws    = (float*)d_ws;
    u16*  xg     = (u16*)ws;              // 8,388,608 u16 (8192 x 1024 fp16, n')
    float* cbuf  = ws   + 4194304;        //   262,144 f32
    float* hs    = cbuf + 262144;         // 2,097,152 f32
    float* part  = hs   + 2097152;        //    32,768 (64 x 512)
    float* stats = part + 262144;         //       512
    u16*  pad_x  = (u16*)(stats + 512);   // 32*18*18*256 fp16
    u16*  pad_h  = pad_x + 2654208;       // 2 x 331,776 (ping-pong)
    u16*  wTx    = pad_h + 663552;        // 1024*2304 (row-major, conv_big)
    u16*  wTf    = wTx   + 2359296;       // 64*72*512 (frag-packed, rec)
    const long PHN = 331776;

    hipMemsetAsync(pad_x, 0, 2654208 * sizeof(u16), stream);   // halos
    hipMemsetAsync(pad_h, 0, 2 * PHN * sizeof(u16), stream);   // halos (once)
    hipLaunchKernelGGL(convert_x_k, dim3(2048), dim3(256), 0, stream, x0, pad_x);

    for (int l = 0; l < 3; ++l) {
        hipLaunchKernelGGL(wprep_all_k, dim3(72, 20), dim3(256), 0, stream,
            Wx[l], Wh[l], wTx, wTf);

        hipLaunchKernelGGL(conv_big_k, dim3(512), dim3(256), 0, stream,
            pad_x, wTx, bb[l], xg);

        // t = 0: gates-only (h0 = 0); writes ph buffer 1
        hipLaunchKernelGGL(gates0_k, dim3(1024), dim3(256), 0, stream,
            xg, cbuf, hs, pad_h + PHN);

        for (int t = 1; t < TSTEPS; ++t) {
            hipLaunchKernelGGL(rec_fused_k, dim3(256), dim3(512), 0, stream,
                pad_h + (t & 1) * PHN, wTf, xg, cbuf, hs,
                pad_h + ((t & 1) ^ 1) * PHN, t);
        }

        hipLaunchKernelGGL(bn_stats1_k, dim3(64), dim3(256), 0, stream, hs, part);
        hipLaunchKernelGGL(bn_stats2_k, dim3(1), dim3(256), 0, stream, part, gg[l], be[l], stats);
        hipLaunchKernelGGL(bn_apply_k, dim3(2048), dim3(256), 0, stream, hs, stats,
            (l < 2) ? pad_x : (u16*)nullptr, (l == 2) ? (float*)d_out : (float*)nullptr);
    }
}